// Round 2
// baseline (247.983 us; speedup 1.0000x reference)
//
#include <hip/hip_runtime.h>
#include <hip/hip_bf16.h>

#define NWIN 2048
#define LOG2E 1.44269504f
#define QSCALE 0.36067376f   // 0.25 * log2(e)

// ws layout (float offsets)
#define OFF_AFF 0        // 512 floats: [b][0..127]=softplus(scale), [128..255]=bias
#define OFF_RPB 512      // 32768 floats: rpb[h][row][col] * LOG2E  (natural, float4-loadable)
#define OFF_WQ  33280    // 49152 bf16 (24576 floats): qkv_w packed frags (16x16x32)
#define OFF_WP  57856    // 16384 bf16 (8192 floats): proj_w packed B-frags (16x16x16)

typedef __attribute__((ext_vector_type(8))) __bf16 bf16x8;
typedef __attribute__((ext_vector_type(4))) float floatx4;
typedef __attribute__((ext_vector_type(4))) short short4v;

#if __has_builtin(__builtin_amdgcn_exp2f)
#define EXP2F __builtin_amdgcn_exp2f
#else
#define EXP2F exp2f
#endif

__global__ __launch_bounds__(256) void prep_kernel(
    const float* __restrict__ frame_type, const float* __restrict__ qkv_w,
    const float* __restrict__ table, const float* __restrict__ proj_w,
    const float* __restrict__ aff_w1, const float* __restrict__ aff_b1,
    const float* __restrict__ aff_w2, const int* __restrict__ rel_index,
    float* __restrict__ ws)
{
  const int gid = blockIdx.x * 256 + threadIdx.x;   // grid covers 49152
  // pack qkv_w into 16x16x32 frag order: idx = ((nt*4+kt)*64+lane)*8+j
  // (A-frag and B-frag share the same lane->element mapping for this shape)
  if (gid < 49152) {
    int j = gid & 7, lane = (gid >> 3) & 63, kt = (gid >> 9) & 3, nt = gid >> 11;
    int n = nt * 16 + (lane & 15);
    int k = kt * 32 + (lane >> 4) * 8 + j;
    ((__bf16*)(ws + OFF_WQ))[gid] = (__bf16)qkv_w[n * 128 + k];
  }
  // pack proj_w into 16x16x16 B-frag order: idx = ((h*8+nt)*64+lane)*4+j
  if (gid < 16384) {
    int j = gid & 3, lane = (gid >> 2) & 63, nt = (gid >> 8) & 7, h = gid >> 11;
    int n = nt * 16 + (lane & 15);
    int k = h * 16 + (lane >> 4) * 4 + j;
    ((__bf16*)(ws + OFF_WP))[gid] = (__bf16)proj_w[n * 128 + k];
  }
  // rpb natural [h][row][col] layout, pre-scaled by log2(e)
  if (gid < 32768) {
    int h = gid >> 12, rem = gid & 4095;
    ws[OFF_RPB + gid] = table[rel_index[rem] * 8 + h] * LOG2E;
  }
  // affine params
  if (gid < 512) {
    int b = gid >> 8, c2 = gid & 255;
    float hd[16];
    #pragma unroll
    for (int j = 0; j < 16; ++j) {
      float t = frame_type[b*2+0]*aff_w1[j*2+0] + frame_type[b*2+1]*aff_w1[j*2+1] + aff_b1[j];
      hd[j] = 1.0f / (1.0f + expf(-t));
    }
    float ap = 0.f;
    #pragma unroll
    for (int j = 0; j < 16; ++j) ap += hd[j] * aff_w2[c2*16 + j];
    float r = (c2 < 128) ? ((ap > 20.f) ? ap : log1pf(expf(ap))) : ap;
    ws[OFF_AFF + gid] = r;
  }
}

// Swapped-QK^T structure:
//   S^T = mfma(K_slot, Q^T): lane holds S[q=row0+l15][j=sigma(jt,quad,r)]
//   sigma(jt,quad,r) = 32*(jt&1) + 8*quad + 4*(jt>>1) + r
//   K rows stored sigma-permuted in sK; V^T stays natural; then exp2'd scores
//   pack IN-LANE into the PV B-frag (pa[0]={jt0,jt2}, pa[1]={jt1,jt3}).
//   Q^T computed per-wave for its own 16 tokens: mfma(Wq_frag, af) -> qa regs.
//   => no Q LDS, no P LDS, one barrier, LDS 35840 B -> 4 blocks/CU.
__global__ __launch_bounds__(256, 4) void attn_kernel(
    const float* __restrict__ x, const float* __restrict__ mask,
    const float* __restrict__ qkv_b, const float* __restrict__ proj_b,
    const float* __restrict__ ws, float* __restrict__ out)
{
  __shared__ __attribute__((aligned(16))) __bf16 sK [64 * 136];  // 17408 B (sigma-permuted rows)
  __shared__ __attribute__((aligned(16))) __bf16 sVT[128 * 72];  // 18432 B
  // total 35840 B -> 4 blocks/CU

  const int w    = blockIdx.x;
  const int b    = w >> 10;
  const int tid  = threadIdx.x;
  const int wv   = tid >> 6;
  const int lane = tid & 63;
  const int quad = lane >> 4;
  const int l15  = lane & 15;
  const int row0 = wv * 16;

  // ---- A/B-fragments of x from global (fp32 -> bf16) ----
  bf16x8 af[4][4];   // [mt][kt]
  {
    const float* xw = x + (size_t)w * 8192;
    #pragma unroll
    for (int mt = 0; mt < 4; ++mt)
      #pragma unroll
      for (int kt = 0; kt < 4; ++kt) {
        const float* p = xw + (mt*16 + l15) * 128 + kt*32 + quad*8;
        float4 f0 = *(const float4*)p;
        float4 f1 = *(const float4*)(p + 4);
        bf16x8 v;
        v[0]=(__bf16)f0.x; v[1]=(__bf16)f0.y; v[2]=(__bf16)f0.z; v[3]=(__bf16)f0.w;
        v[4]=(__bf16)f1.x; v[5]=(__bf16)f1.y; v[6]=(__bf16)f1.z; v[7]=(__bf16)f1.w;
        af[mt][kt] = v;
      }
  }

  const __bf16* wq = (const __bf16*)(ws + OFF_WQ);

  // ---- K,V slices: wave handles nt in {8+wv, 12+wv, 16+wv, 20+wv} over all mt ----
  {
    #pragma unroll
    for (int t = 0; t < 4; ++t) {
      const int nt = 8 + ((t >> 1) << 3) + ((t & 1) << 2) + wv;
      bf16x8 bfr[4];
      #pragma unroll
      for (int kt = 0; kt < 4; ++kt)
        bfr[kt] = *(const bf16x8*)(wq + ((size_t)(nt*4 + kt) * 64 + lane) * 8);
      const float bias = qkv_b[nt*16 + l15];
      const int col = nt*16 + l15;
      #pragma unroll
      for (int mt = 0; mt < 4; ++mt) {
        floatx4 acc = {bias, bias, bias, bias};
        #pragma unroll
        for (int kt = 0; kt < 4; ++kt)
          acc = __builtin_amdgcn_mfma_f32_16x16x32_bf16(af[mt][kt], bfr[kt], acc, 0, 0, 0);
        if (nt < 16) {          // K: sigma-permuted row placement
          const int c = col - 128;
          const int srow0 = ((((quad & 1) << 1) + (mt >> 1)) << 4)
                          + ((((mt & 1) << 1) | (quad >> 1)) << 2);
          #pragma unroll
          for (int r = 0; r < 4; ++r) sK[(srow0 + r)*136 + c] = (__bf16)acc[r];
        } else {                // V, modulated, transposed (natural token order)
          const int c = col - 256;
          const float sp = ws[OFF_AFF + b*256 + c];
          const float bp = ws[OFF_AFF + b*256 + 128 + c];
          const int rowb = mt*16 + quad*4;
          #pragma unroll
          for (int r = 0; r < 4; ++r) sVT[c*72 + rowb + r] = (__bf16)fmaf(sp, acc[r], bp);
        }
      }
    }
  }

  // ---- Q^T GEMM into registers: own 16 tokens, all 8 head-slices ----
  // aq = af[wv] via wave-uniform branches (no runtime register indexing)
  bf16x8 aq[4];
  #pragma unroll
  for (int kt = 0; kt < 4; ++kt) aq[kt] = af[0][kt];
  #pragma unroll
  for (int mt = 1; mt < 4; ++mt)
    if (wv == mt) {
      #pragma unroll
      for (int kt = 0; kt < 4; ++kt) aq[kt] = af[mt][kt];
    }

  short4v qa[8];   // qa[h] = B-frag: Q[row0+l15][h*16+quad*4+j] * QSCALE
  {
    #pragma unroll
    for (int nt = 0; nt < 8; ++nt) {
      bf16x8 bfr[4];
      #pragma unroll
      for (int kt = 0; kt < 4; ++kt)
        bfr[kt] = *(const bf16x8*)(wq + ((size_t)(nt*4 + kt) * 64 + lane) * 8);
      floatx4 acc = *(const floatx4*)(qkv_b + nt*16 + quad*4);
      #pragma unroll
      for (int kt = 0; kt < 4; ++kt)
        acc = __builtin_amdgcn_mfma_f32_16x16x32_bf16(bfr[kt], aq[kt], acc, 0, 0, 0);
      union { short4v s; __bf16 h4[4]; } u;
      #pragma unroll
      for (int r = 0; r < 4; ++r) u.h4[r] = (__bf16)(acc[r] * QSCALE);
      qa[nt] = u.s;
    }
  }
  __syncthreads();   // the only barrier

  // ---- mask hoist (pre-scaled by log2e), float4 over r at sigma j-offsets ----
  floatx4 mv[4];
  {
    const float* mrow = mask + (size_t)(w & 1023) * 4096 + (row0 + l15) * 64;
    #pragma unroll
    for (int jt = 0; jt < 4; ++jt) {
      const int joff = ((jt & 1) << 5) + ((jt >> 1) << 2) + (quad << 3);
      floatx4 m4 = *(const floatx4*)(mrow + joff);
      #pragma unroll
      for (int r = 0; r < 4; ++r) mv[jt][r] = m4[r] * LOG2E;
    }
  }

  floatx4 pacc[8];
  #pragma unroll
  for (int nt = 0; nt < 8; ++nt) {
    float pb = proj_b[nt*16 + l15];
    pacc[nt] = (floatx4){pb, pb, pb, pb};
  }

  bf16x8 ones;
  #pragma unroll
  for (int i = 0; i < 8; ++i) ones[i] = (__bf16)1.0f;

  const float* rpb = ws + OFF_RPB;
  const __bf16* wp = (const __bf16*)(ws + OFF_WP);

  // ---- per-head: S^T=mfma(K,Q) -> exp2 in-lane -> pa -> O=PV -> proj slice ----
  #pragma unroll
  for (int h = 0; h < 8; ++h) {
    floatx4 rq[4];
    #pragma unroll
    for (int jt = 0; jt < 4; ++jt) {
      const int joff = ((jt & 1) << 5) + ((jt >> 1) << 2) + (quad << 3);
      rq[jt] = *(const floatx4*)(rpb + h*4096 + (row0 + l15)*64 + joff);
    }
    short4v kb[4];
    #pragma unroll
    for (int jt = 0; jt < 4; ++jt)
      kb[jt] = *(const short4v*)(&sK[(jt*16 + l15)*136 + h*16 + quad*4]);

    floatx4 s[4];
    #pragma unroll
    for (int jt = 0; jt < 4; ++jt) {
      floatx4 ci = rq[jt] + mv[jt];
      s[jt] = __builtin_amdgcn_mfma_f32_16x16x16bf16_1k(kb[jt], qa[h], ci, 0, 0, 0);
    }

    // unnormalized probs; pack in-lane into PV B-frags (sigma makes this exact)
    union { bf16x8 v; __bf16 e[8]; } p0, p1;
    #pragma unroll
    for (int r = 0; r < 4; ++r) {
      p0.e[r]     = (__bf16)EXP2F(s[0][r]);
      p0.e[4 + r] = (__bf16)EXP2F(s[2][r]);
      p1.e[r]     = (__bf16)EXP2F(s[1][r]);
      p1.e[4 + r] = (__bf16)EXP2F(s[3][r]);
    }

    bf16x8 vb0 = *(const bf16x8*)(&sVT[(h*16 + l15)*72 + quad*8]);
    bf16x8 vb1 = *(const bf16x8*)(&sVT[(h*16 + l15)*72 + 32 + quad*8]);
    floatx4 o2 = {0.f,0.f,0.f,0.f}, sm = {0.f,0.f,0.f,0.f};
    o2 = __builtin_amdgcn_mfma_f32_16x16x32_bf16(vb0, p0.v, o2, 0, 0, 0);
    sm = __builtin_amdgcn_mfma_f32_16x16x32_bf16(ones, p0.v, sm, 0, 0, 0);
    o2 = __builtin_amdgcn_mfma_f32_16x16x32_bf16(vb1, p1.v, o2, 0, 0, 0);
    sm = __builtin_amdgcn_mfma_f32_16x16x32_bf16(ones, p1.v, sm, 0, 0, 0);

    const float inv = 1.0f / sm[0];
    // lane holds O[row0+l15][h*16+quad*4+r] == proj A-frag (K=16 slice)
    union { short4v s; __bf16 hh[4]; } u;
    #pragma unroll
    for (int r = 0; r < 4; ++r) u.hh[r] = (__bf16)(o2[r] * inv);

    short4v wpf[8];
    #pragma unroll
    for (int nt = 0; nt < 8; ++nt)
      wpf[nt] = *(const short4v*)(wp + ((size_t)(h*8 + nt)*64 + lane)*4);
    #pragma unroll
    for (int nt = 0; nt < 8; ++nt)
      pacc[nt] = __builtin_amdgcn_mfma_f32_16x16x16bf16_1k(u.s, wpf[nt], pacc[nt], 0, 0, 0);
  }

  // ---- store ----
  {
    float* ow = out + (size_t)w * 8192;
    #pragma unroll
    for (int nt = 0; nt < 8; ++nt)
      #pragma unroll
      for (int r = 0; r < 4; ++r)
        ow[(row0 + quad*4 + r)*128 + nt*16 + l15] = pacc[nt][r];
  }
}

extern "C" void kernel_launch(void* const* d_in, const int* in_sizes, int n_in,
                              void* d_out, int out_size, void* d_ws, size_t ws_size,
                              hipStream_t stream)
{
  const float* x          = (const float*)d_in[0];
  const float* mask       = (const float*)d_in[1];
  const float* frame_type = (const float*)d_in[2];
  const float* qkv_w      = (const float*)d_in[3];
  const float* qkv_b      = (const float*)d_in[4];
  const float* table      = (const float*)d_in[5];
  const float* proj_w     = (const float*)d_in[6];
  const float* proj_b     = (const float*)d_in[7];
  const float* aff_w1     = (const float*)d_in[8];
  const float* aff_b1     = (const float*)d_in[9];
  const float* aff_w2     = (const float*)d_in[10];
  const int*   rel_index  = (const int*)d_in[11];
  float* ws   = (float*)d_ws;
  float* outp = (float*)d_out;

  prep_kernel<<<192, 256, 0, stream>>>(frame_type, qkv_w, table, proj_w,
                                       aff_w1, aff_b1, aff_w2, rel_index, ws);
  attn_kernel<<<NWIN, 256, 0, stream>>>(x, mask, qkv_b, proj_b, ws, outp);
}

// Round 3
// 221.291 us; speedup vs baseline: 1.1206x; 1.1206x over previous
//
#include <hip/hip_runtime.h>
#include <hip/hip_bf16.h>

#define NWIN 2048
#define LOG2E 1.44269504f
#define QSCALE 0.36067376f   // 0.25 * log2(e)

// ws layout (float offsets)
#define OFF_AFF 0        // 512 floats: [b][0..127]=softplus(scale), [128..255]=bias
#define OFF_RPB 512      // 32768 floats: rpb[h][row][col] * LOG2E  (natural, float4-loadable)
#define OFF_WQ  33280    // 49152 bf16 (24576 floats): qkv_w packed frags (16x16x32)
#define OFF_WP  57856    // 16384 bf16 (8192 floats): proj_w packed B-frags (16x16x16)

typedef __attribute__((ext_vector_type(8))) __bf16 bf16x8;
typedef __attribute__((ext_vector_type(4))) float floatx4;
typedef __attribute__((ext_vector_type(4))) short short4v;

#if __has_builtin(__builtin_amdgcn_exp2f)
#define EXP2F __builtin_amdgcn_exp2f
#else
#define EXP2F exp2f
#endif

__global__ __launch_bounds__(256) void prep_kernel(
    const float* __restrict__ frame_type, const float* __restrict__ qkv_w,
    const float* __restrict__ table, const float* __restrict__ proj_w,
    const float* __restrict__ aff_w1, const float* __restrict__ aff_b1,
    const float* __restrict__ aff_w2, const int* __restrict__ rel_index,
    float* __restrict__ ws)
{
  const int gid = blockIdx.x * 256 + threadIdx.x;   // grid covers 49152
  // pack qkv_w into 16x16x32 frag order: idx = ((nt*4+kt)*64+lane)*8+j
  // (A-frag and B-frag share the same lane->element mapping for this shape)
  if (gid < 49152) {
    int j = gid & 7, lane = (gid >> 3) & 63, kt = (gid >> 9) & 3, nt = gid >> 11;
    int n = nt * 16 + (lane & 15);
    int k = kt * 32 + (lane >> 4) * 8 + j;
    ((__bf16*)(ws + OFF_WQ))[gid] = (__bf16)qkv_w[n * 128 + k];
  }
  // pack proj_w into 16x16x16 B-frag order: idx = ((h*8+nt)*64+lane)*4+j
  if (gid < 16384) {
    int j = gid & 3, lane = (gid >> 2) & 63, nt = (gid >> 8) & 7, h = gid >> 11;
    int n = nt * 16 + (lane & 15);
    int k = h * 16 + (lane >> 4) * 4 + j;
    ((__bf16*)(ws + OFF_WP))[gid] = (__bf16)proj_w[n * 128 + k];
  }
  // rpb natural [h][row][col] layout, pre-scaled by log2(e)
  if (gid < 32768) {
    int h = gid >> 12, rem = gid & 4095;
    ws[OFF_RPB + gid] = table[rel_index[rem] * 8 + h] * LOG2E;
  }
  // affine params
  if (gid < 512) {
    int b = gid >> 8, c2 = gid & 255;
    float hd[16];
    #pragma unroll
    for (int j = 0; j < 16; ++j) {
      float t = frame_type[b*2+0]*aff_w1[j*2+0] + frame_type[b*2+1]*aff_w1[j*2+1] + aff_b1[j];
      hd[j] = 1.0f / (1.0f + expf(-t));
    }
    float ap = 0.f;
    #pragma unroll
    for (int j = 0; j < 16; ++j) ap += hd[j] * aff_w2[c2*16 + j];
    float r = (c2 < 128) ? ((ap > 20.f) ? ap : log1pf(expf(ap))) : ap;
    ws[OFF_AFF + gid] = r;
  }
}

// Swapped-QK^T structure:
//   S^T = mfma(K_slot, Q^T): lane holds S[q=row0+l15][j=sigma(jt,quad,r)]
//   sigma(jt,quad,r) = 32*(jt&1) + 8*quad + 4*(jt>>1) + r
//   K rows stored sigma-permuted in sK; V^T stays natural; then exp2'd scores
//   pack IN-LANE into the PV B-frag (pa[0]={jt0,jt2}, pa[1]={jt1,jt3}).
//   Q^T computed per-wave for its own 16 tokens: mfma(Wq_frag, af) -> qa regs.
//   => no Q LDS, no P LDS, one barrier, LDS 35840 B.
// launch_bounds (256,3): cap ~170 VGPR. Round-2 A/B: (256,4) forced VGPR=64 +
//   scratch spills (+110 MB/dispatch HBM traffic, dur 112->139 us). If actual
//   alloc lands <=128, runtime still reaches the LDS limit of 4 blocks/CU.
// h-loop is `#pragma unroll 1`: full unroll blew register pressure (round-2);
//   wave-uniform dynamic qa[h] lowers to m0-indexed register access, not
//   scratch (verified by old kernel: WRITE_SIZE == output size at VGPR=84).
__global__ __launch_bounds__(256, 3) void attn_kernel(
    const float* __restrict__ x, const float* __restrict__ mask,
    const float* __restrict__ qkv_b, const float* __restrict__ proj_b,
    const float* __restrict__ ws, float* __restrict__ out)
{
  __shared__ __attribute__((aligned(16))) __bf16 sK [64 * 136];  // 17408 B (sigma-permuted rows)
  __shared__ __attribute__((aligned(16))) __bf16 sVT[128 * 72];  // 18432 B
  // total 35840 B

  const int w    = blockIdx.x;
  const int b    = w >> 10;
  const int tid  = threadIdx.x;
  const int wv   = tid >> 6;
  const int lane = tid & 63;
  const int quad = lane >> 4;
  const int l15  = lane & 15;
  const int row0 = wv * 16;

  // ---- A/B-fragments of x from global (fp32 -> bf16) ----
  bf16x8 af[4][4];   // [mt][kt]
  {
    const float* xw = x + (size_t)w * 8192;
    #pragma unroll
    for (int mt = 0; mt < 4; ++mt)
      #pragma unroll
      for (int kt = 0; kt < 4; ++kt) {
        const float* p = xw + (mt*16 + l15) * 128 + kt*32 + quad*8;
        float4 f0 = *(const float4*)p;
        float4 f1 = *(const float4*)(p + 4);
        bf16x8 v;
        v[0]=(__bf16)f0.x; v[1]=(__bf16)f0.y; v[2]=(__bf16)f0.z; v[3]=(__bf16)f0.w;
        v[4]=(__bf16)f1.x; v[5]=(__bf16)f1.y; v[6]=(__bf16)f1.z; v[7]=(__bf16)f1.w;
        af[mt][kt] = v;
      }
  }

  const __bf16* wq = (const __bf16*)(ws + OFF_WQ);

  // ---- K,V slices: wave handles nt in {8+wv, 12+wv, 16+wv, 20+wv} over all mt ----
  {
    #pragma unroll
    for (int t = 0; t < 4; ++t) {
      const int nt = 8 + ((t >> 1) << 3) + ((t & 1) << 2) + wv;
      bf16x8 bfr[4];
      #pragma unroll
      for (int kt = 0; kt < 4; ++kt)
        bfr[kt] = *(const bf16x8*)(wq + ((size_t)(nt*4 + kt) * 64 + lane) * 8);
      const float bias = qkv_b[nt*16 + l15];
      const int col = nt*16 + l15;
      #pragma unroll
      for (int mt = 0; mt < 4; ++mt) {
        floatx4 acc = {bias, bias, bias, bias};
        #pragma unroll
        for (int kt = 0; kt < 4; ++kt)
          acc = __builtin_amdgcn_mfma_f32_16x16x32_bf16(af[mt][kt], bfr[kt], acc, 0, 0, 0);
        if (nt < 16) {          // K: sigma-permuted row placement
          const int c = col - 128;
          const int srow0 = ((((quad & 1) << 1) + (mt >> 1)) << 4)
                          + ((((mt & 1) << 1) | (quad >> 1)) << 2);
          #pragma unroll
          for (int r = 0; r < 4; ++r) sK[(srow0 + r)*136 + c] = (__bf16)acc[r];
        } else {                // V, modulated, transposed (natural token order)
          const int c = col - 256;
          const float sp = ws[OFF_AFF + b*256 + c];
          const float bp = ws[OFF_AFF + b*256 + 128 + c];
          const int rowb = mt*16 + quad*4;
          #pragma unroll
          for (int r = 0; r < 4; ++r) sVT[c*72 + rowb + r] = (__bf16)fmaf(sp, acc[r], bp);
        }
      }
    }
  }

  // ---- Q^T GEMM into registers: own 16 tokens, all 8 head-slices ----
  // aq = af[wv] via wave-uniform branches (no runtime register indexing)
  bf16x8 aq[4];
  #pragma unroll
  for (int kt = 0; kt < 4; ++kt) aq[kt] = af[0][kt];
  #pragma unroll
  for (int mt = 1; mt < 4; ++mt)
    if (wv == mt) {
      #pragma unroll
      for (int kt = 0; kt < 4; ++kt) aq[kt] = af[mt][kt];
    }

  short4v qa[8];   // qa[h] = B-frag: Q[row0+l15][h*16+quad*4+j] * QSCALE
  {
    #pragma unroll
    for (int nt = 0; nt < 8; ++nt) {
      bf16x8 bfr[4];
      #pragma unroll
      for (int kt = 0; kt < 4; ++kt)
        bfr[kt] = *(const bf16x8*)(wq + ((size_t)(nt*4 + kt) * 64 + lane) * 8);
      floatx4 acc = *(const floatx4*)(qkv_b + nt*16 + quad*4);
      #pragma unroll
      for (int kt = 0; kt < 4; ++kt)
        acc = __builtin_amdgcn_mfma_f32_16x16x32_bf16(bfr[kt], aq[kt], acc, 0, 0, 0);
      union { short4v s; __bf16 h4[4]; } u;
      #pragma unroll
      for (int r = 0; r < 4; ++r) u.h4[r] = (__bf16)(acc[r] * QSCALE);
      qa[nt] = u.s;
    }
  }
  __syncthreads();   // the only barrier

  // ---- mask hoist (pre-scaled by log2e), float4 over r at sigma j-offsets ----
  floatx4 mv[4];
  {
    const float* mrow = mask + (size_t)(w & 1023) * 4096 + (row0 + l15) * 64;
    #pragma unroll
    for (int jt = 0; jt < 4; ++jt) {
      const int joff = ((jt & 1) << 5) + ((jt >> 1) << 2) + (quad << 3);
      floatx4 m4 = *(const floatx4*)(mrow + joff);
      #pragma unroll
      for (int r = 0; r < 4; ++r) mv[jt][r] = m4[r] * LOG2E;
    }
  }

  floatx4 pacc[8];
  #pragma unroll
  for (int nt = 0; nt < 8; ++nt) {
    float pb = proj_b[nt*16 + l15];
    pacc[nt] = (floatx4){pb, pb, pb, pb};
  }

  bf16x8 ones;
  #pragma unroll
  for (int i = 0; i < 8; ++i) ones[i] = (__bf16)1.0f;

  const float* rpb = ws + OFF_RPB;
  const __bf16* wp = (const __bf16*)(ws + OFF_WP);

  // ---- per-head: S^T=mfma(K,Q) -> exp2 in-lane -> pa -> O=PV -> proj slice ----
  #pragma unroll 1
  for (int h = 0; h < 8; ++h) {
    floatx4 rq[4];
    #pragma unroll
    for (int jt = 0; jt < 4; ++jt) {
      const int joff = ((jt & 1) << 5) + ((jt >> 1) << 2) + (quad << 3);
      rq[jt] = *(const floatx4*)(rpb + h*4096 + (row0 + l15)*64 + joff);
    }
    short4v wpf[8];
    #pragma unroll
    for (int nt = 0; nt < 8; ++nt)
      wpf[nt] = *(const short4v*)(wp + ((size_t)(h*8 + nt)*64 + lane)*4);
    short4v kb[4];
    #pragma unroll
    for (int jt = 0; jt < 4; ++jt)
      kb[jt] = *(const short4v*)(&sK[(jt*16 + l15)*136 + h*16 + quad*4]);

    floatx4 s[4];
    #pragma unroll
    for (int jt = 0; jt < 4; ++jt) {
      floatx4 ci = rq[jt] + mv[jt];
      s[jt] = __builtin_amdgcn_mfma_f32_16x16x16bf16_1k(kb[jt], qa[h], ci, 0, 0, 0);
    }

    // unnormalized probs; pack in-lane into PV B-frags (sigma makes this exact)
    union { bf16x8 v; __bf16 e[8]; } p0, p1;
    #pragma unroll
    for (int r = 0; r < 4; ++r) {
      p0.e[r]     = (__bf16)EXP2F(s[0][r]);
      p0.e[4 + r] = (__bf16)EXP2F(s[2][r]);
      p1.e[r]     = (__bf16)EXP2F(s[1][r]);
      p1.e[4 + r] = (__bf16)EXP2F(s[3][r]);
    }

    bf16x8 vb0 = *(const bf16x8*)(&sVT[(h*16 + l15)*72 + quad*8]);
    bf16x8 vb1 = *(const bf16x8*)(&sVT[(h*16 + l15)*72 + 32 + quad*8]);
    floatx4 o2 = {0.f,0.f,0.f,0.f}, sm = {0.f,0.f,0.f,0.f};
    o2 = __builtin_amdgcn_mfma_f32_16x16x32_bf16(vb0, p0.v, o2, 0, 0, 0);
    sm = __builtin_amdgcn_mfma_f32_16x16x32_bf16(ones, p0.v, sm, 0, 0, 0);
    o2 = __builtin_amdgcn_mfma_f32_16x16x32_bf16(vb1, p1.v, o2, 0, 0, 0);
    sm = __builtin_amdgcn_mfma_f32_16x16x32_bf16(ones, p1.v, sm, 0, 0, 0);

    const float inv = 1.0f / sm[0];
    // lane holds O[row0+l15][h*16+quad*4+r] == proj A-frag (K=16 slice)
    union { short4v s; __bf16 hh[4]; } u;
    #pragma unroll
    for (int r = 0; r < 4; ++r) u.hh[r] = (__bf16)(o2[r] * inv);

    #pragma unroll
    for (int nt = 0; nt < 8; ++nt)
      pacc[nt] = __builtin_amdgcn_mfma_f32_16x16x16bf16_1k(u.s, wpf[nt], pacc[nt], 0, 0, 0);
  }

  // ---- store ----
  {
    float* ow = out + (size_t)w * 8192;
    #pragma unroll
    for (int nt = 0; nt < 8; ++nt)
      #pragma unroll
      for (int r = 0; r < 4; ++r)
        ow[(row0 + quad*4 + r)*128 + nt*16 + l15] = pacc[nt][r];
  }
}

extern "C" void kernel_launch(void* const* d_in, const int* in_sizes, int n_in,
                              void* d_out, int out_size, void* d_ws, size_t ws_size,
                              hipStream_t stream)
{
  const float* x          = (const float*)d_in[0];
  const float* mask       = (const float*)d_in[1];
  const float* frame_type = (const float*)d_in[2];
  const float* qkv_w      = (const float*)d_in[3];
  const float* qkv_b      = (const float*)d_in[4];
  const float* table      = (const float*)d_in[5];
  const float* proj_w     = (const float*)d_in[6];
  const float* proj_b     = (const float*)d_in[7];
  const float* aff_w1     = (const float*)d_in[8];
  const float* aff_b1     = (const float*)d_in[9];
  const float* aff_w2     = (const float*)d_in[10];
  const int*   rel_index  = (const int*)d_in[11];
  float* ws   = (float*)d_ws;
  float* outp = (float*)d_out;

  prep_kernel<<<192, 256, 0, stream>>>(frame_type, qkv_w, table, proj_w,
                                       aff_w1, aff_b1, aff_w2, rel_index, ws);
  attn_kernel<<<NWIN, 256, 0, stream>>>(x, mask, qkv_b, proj_b, ws, outp);
}